// Round 9
// baseline (2670.572 us; speedup 1.0000x reference)
//
#include <hip/hip_runtime.h>
#include <hip/hip_fp16.h>
#include <math.h>

// Problem constants (fixed by the reference)
#define NN 20000
#define EE 5000
#define DD 128
#define ATT 32
#define NUM_LAYERS 4
#define LN_EPS 1e-5f
#define DEG_EPS 1e-12f

#define ECAP 320
#define NCAP 128
#define CSTRIDE 32

typedef float vfloat4 __attribute__((ext_vector_type(4)));
typedef _Float16 f16;
typedef f16 f16x8 __attribute__((ext_vector_type(8)));
typedef float f32x4 __attribute__((ext_vector_type(4)));
typedef unsigned short ushort_t;
typedef unsigned int uint_t;

__device__ inline unsigned pack2h(float x, float y) {
    return __builtin_bit_cast(unsigned, __floats2half2_rn(x, y));
}
__device__ inline void acc8(float* a, uint4 u) {
    __half2 h;
    h = __builtin_bit_cast(__half2, u.x); a[0] += __low2float(h); a[1] += __high2float(h);
    h = __builtin_bit_cast(__half2, u.y); a[2] += __low2float(h); a[3] += __high2float(h);
    h = __builtin_bit_cast(__half2, u.z); a[4] += __low2float(h); a[5] += __high2float(h);
    h = __builtin_bit_cast(__half2, u.w); a[6] += __low2float(h); a[7] += __high2float(h);
}

// ===========================================================================
// R16: DENSE MFMA GEMM PATH. The scattered-gather design is structurally
// capped (~430us of unattributable cold-gather cost; R9-R15 refuted launch
// overhead, pipeline depth, cache persistence, and L2 capacity as levers).
// Replace per-layer gathers with dense fp16 GEMMs streaming H16 (200 MB,
// coalesced) per pass:  em = de_inv*(H^T @ x);  x' = LN(dv_inv*(H @ em)+x0).
// mfma_f32_16x16x32_f16, fp32 accumulate (numerically == gather path).
// Workspace ~230 MB -> guarded by ws_size with the R14 path as fallback.
// ===========================================================================

#define LP 36   // LDS row pad in ushorts (72 B): b64-aligned, conflict-free frag reads

__device__ inline f16x8 ld8(const ushort_t* p) {
    // two ds_read_b64 (rows are 8B-aligned, not 16B)
    uint2 a = *(const uint2*)p;
    uint2 b = *(const uint2*)(p + 4);
    union { uint_t u[4]; f16x8 v; } x;
    x.u[0] = a.x; x.u[1] = a.y; x.u[2] = b.x; x.u[3] = b.y;
    return x.v;
}

// ---------------------------------------------------------------------------
// Convert H (fp32) -> H16 (fp16) in ONE nontemporal pass; node degrees via
// wave reduce; edge degrees via padded-line atomics (R8-proven pattern);
// x0 -> fp16 xh fused.
// ---------------------------------------------------------------------------
__global__ __launch_bounds__(256) void convert_h(
    const float* __restrict__ H, __half* __restrict__ H16,
    int* __restrict__ cur, int* __restrict__ nc,
    const float* __restrict__ x0, __half* __restrict__ xh) {
    const int n = blockIdx.x;
    const int t = threadIdx.x;
    __shared__ int red[4];
    int cnt = 0;
    const vfloat4* row = reinterpret_cast<const vfloat4*>(H + (size_t)n * EE);
    uint2* orow = reinterpret_cast<uint2*>(H16 + (size_t)n * EE);
    for (int i = t; i < EE / 4; i += 256) {
        const vfloat4 h = __builtin_nontemporal_load(row + i);
        uint2 u; u.x = pack2h(h.x, h.y); u.y = pack2h(h.z, h.w);
        orow[i] = u;
        const int e = i * 4;
        if (h.x != 0.0f) { cnt++; atomicAdd(&cur[(e + 0) << 5], 1); }
        if (h.y != 0.0f) { cnt++; atomicAdd(&cur[(e + 1) << 5], 1); }
        if (h.z != 0.0f) { cnt++; atomicAdd(&cur[(e + 2) << 5], 1); }
        if (h.w != 0.0f) { cnt++; atomicAdd(&cur[(e + 3) << 5], 1); }
    }
    for (int off = 32; off > 0; off >>= 1) cnt += __shfl_down(cnt, off);
    if ((t & 63) == 0) red[t >> 6] = cnt;
    if (t < 64) {
        const float2 v = reinterpret_cast<const float2*>(x0 + (size_t)n * DD)[t];
        reinterpret_cast<unsigned*>(xh + (size_t)n * DD)[t] = pack2h(v.x, v.y);
    }
    __syncthreads();
    if (t == 0) nc[n] = red[0] + red[1] + red[2] + red[3];
}

// ---------------------------------------------------------------------------
// GEMM-E: Cacc[e][d] += sum_n H16[n][e] * xh[n][d].  K=20000 split into 4
// chunks of 5000; 79 e-tiles (BM=64) x 4 chunks = 316 blocks; BN=128 full.
// A staged transposed (H16 is [k][m]); B staged transposed ([k][d]->[d][k]).
// fp32 atomic accumulate into Cacc (pre-zeroed; re-zeroed by ep_edge).
// ---------------------------------------------------------------------------
__global__ __launch_bounds__(256) void gemm_e(
    const __half* __restrict__ H16, const __half* __restrict__ xh,
    float* __restrict__ Cacc) {
    __shared__ ushort_t Asm[64][LP];
    __shared__ ushort_t Bsm[128][LP];
    const int bid = blockIdx.x;
    const int mt_ = bid % 79, kc = bid / 79;
    const int e0 = mt_ * 64;
    const int kbeg = kc * 5000, kend = kbeg + 5000;
    const int t = threadIdx.x;
    const int w = t >> 6, l = t & 63;
    const int lr = l & 15, lk = l >> 4;
    f32x4 acc[4][2];
#pragma unroll
    for (int m = 0; m < 4; m++)
#pragma unroll
        for (int nt = 0; nt < 2; nt++) acc[m][nt] = (f32x4){0.f, 0.f, 0.f, 0.f};
    const int B_kp = t >> 4, B_dg = t & 15;
    const int A_kp = (t & 127) >> 3, A_eg = t & 7;
    const ushort_t* H16u = (const ushort_t*)H16;
    const ushort_t* xhu = (const ushort_t*)xh;
    for (int k0 = kbeg; k0 < kend; k0 += 32) {
        uint4 r0 = {0,0,0,0}, r1 = {0,0,0,0}, s0 = {0,0,0,0}, s1 = {0,0,0,0};
        {
            const int ka = k0 + 2 * B_kp, kb = ka + 1;
            if (ka < kend) r0 = *(const uint4*)(xhu + (size_t)ka * DD + B_dg * 8);
            if (kb < kend) r1 = *(const uint4*)(xhu + (size_t)kb * DD + B_dg * 8);
        }
        if (t < 128) {
            const int ka = k0 + 2 * A_kp, kb = ka + 1;
            if (ka < kend) s0 = *(const uint4*)(H16u + (size_t)ka * EE + e0 + A_eg * 8);
            if (kb < kend) s1 = *(const uint4*)(H16u + (size_t)kb * EE + e0 + A_eg * 8);
        }
        __syncthreads();   // previous tile's frag reads complete
        {
            const ushort_t* p0 = (const ushort_t*)&r0;
            const ushort_t* p1 = (const ushort_t*)&r1;
#pragma unroll
            for (int i = 0; i < 8; i++) {
                *(uint_t*)&Bsm[B_dg * 8 + i][2 * B_kp] =
                    (uint_t)p0[i] | ((uint_t)p1[i] << 16);
            }
            if (t < 128) {
                const ushort_t* q0 = (const ushort_t*)&s0;
                const ushort_t* q1 = (const ushort_t*)&s1;
#pragma unroll
                for (int i = 0; i < 8; i++) {
                    *(uint_t*)&Asm[A_eg * 8 + i][2 * A_kp] =
                        (uint_t)q0[i] | ((uint_t)q1[i] << 16);
                }
            }
        }
        __syncthreads();
        f16x8 bfrag[2], afrag[4];
#pragma unroll
        for (int nt = 0; nt < 2; nt++)
            bfrag[nt] = ld8(&Bsm[w * 32 + nt * 16 + lr][lk * 8]);
#pragma unroll
        for (int m = 0; m < 4; m++)
            afrag[m] = ld8(&Asm[m * 16 + lr][lk * 8]);
#pragma unroll
        for (int m = 0; m < 4; m++)
#pragma unroll
            for (int nt = 0; nt < 2; nt++)
                acc[m][nt] = __builtin_amdgcn_mfma_f32_16x16x32_f16(
                    afrag[m], bfrag[nt], acc[m][nt], 0, 0, 0);
    }
    // C/D layout [m89-verified]: col = l&15, row = (l>>4)*4 + r
#pragma unroll
    for (int m = 0; m < 4; m++)
#pragma unroll
        for (int nt = 0; nt < 2; nt++)
#pragma unroll
            for (int r = 0; r < 4; r++) {
                const int e = e0 + m * 16 + lk * 4 + r;      // < 5056 (Cacc padded)
                const int d = w * 32 + nt * 16 + lr;
                atomicAdd(&Cacc[(size_t)e * DD + d], acc[m][nt][r]);
            }
}

// ---------------------------------------------------------------------------
// Edge epilogue: scale Cacc by de_inv -> emean fp16 (layers) or by
// 1/max(de,1) -> eout fp32 (final). Re-zeros Cacc for the next layer.
// Grid 2528 x 256 covers the padded 5056 rows.
// ---------------------------------------------------------------------------
__global__ __launch_bounds__(256) void ep_edge(
    float* __restrict__ Cacc, const int* __restrict__ cur,
    __half* __restrict__ em, float* __restrict__ eout, const int isFinal) {
    const int e = blockIdx.x * 2 + (threadIdx.x >> 7);
    const int d = threadIdx.x & 127;
    const float v = Cacc[(size_t)e * DD + d];
    Cacc[(size_t)e * DD + d] = 0.0f;
    if (e >= EE) return;
    const float de = (float)cur[e << 5];
    if (!isFinal) {
        const float s = 1.0f / fmaxf(de, DEG_EPS);
        em[(size_t)e * DD + d] = (__half)(v * s);
    } else {
        const float s = 1.0f / fmaxf(de, 1.0f);
        eout[(size_t)e * DD + d] = v * s;
    }
}

// ---------------------------------------------------------------------------
// GEMM-N + fused LN: x'[n][d] = LN(dv_inv * sum_e H16[n][e]*em[e][d] + x0).
// 313 blocks (BM=64 nodes), K=5000 full (no split-K -> epilogue fusable).
// A is naturally k-minor (H16 row-major); B staged transposed from em.
// ---------------------------------------------------------------------------
__global__ __launch_bounds__(256) void gemm_n(
    const __half* __restrict__ H16, const __half* __restrict__ em,
    const int* __restrict__ nc, const float* __restrict__ x0,
    const float* __restrict__ gamma, const float* __restrict__ beta,
    __half* __restrict__ xh) {
    __shared__ ushort_t Asm[64][LP];
    __shared__ ushort_t Bsm[128][LP];
    __shared__ float Csm[64][DD];
    const int n0 = blockIdx.x * 64;
    const int t = threadIdx.x;
    const int w = t >> 6, l = t & 63;
    const int lr = l & 15, lk = l >> 4;
    f32x4 acc[4][2];
#pragma unroll
    for (int m = 0; m < 4; m++)
#pragma unroll
        for (int nt = 0; nt < 2; nt++) acc[m][nt] = (f32x4){0.f, 0.f, 0.f, 0.f};
    const int A_m = t >> 2, A_kg = t & 3;
    const int B_kp = t >> 4, B_dg = t & 15;
    const ushort_t* H16u = (const ushort_t*)H16;
    const ushort_t* emu = (const ushort_t*)em;
    for (int k0 = 0; k0 < EE; k0 += 32) {
        uint4 r0 = {0,0,0,0}, r1 = {0,0,0,0}, s0 = {0,0,0,0};
        {
            const int ka = k0 + 2 * B_kp, kb = ka + 1;
            if (ka < EE) r0 = *(const uint4*)(emu + (size_t)ka * DD + B_dg * 8);
            if (kb < EE) r1 = *(const uint4*)(emu + (size_t)kb * DD + B_dg * 8);
        }
        if (n0 + A_m < NN && k0 + A_kg * 8 < EE)   // EE%8==0: no straddle
            s0 = *(const uint4*)(H16u + (size_t)(n0 + A_m) * EE + k0 + A_kg * 8);
        __syncthreads();
        {
            const ushort_t* p0 = (const ushort_t*)&r0;
            const ushort_t* p1 = (const ushort_t*)&r1;
#pragma unroll
            for (int i = 0; i < 8; i++) {
                *(uint_t*)&Bsm[B_dg * 8 + i][2 * B_kp] =
                    (uint_t)p0[i] | ((uint_t)p1[i] << 16);
            }
            // A: natural k-minor; two 8B LDS writes (rows are 8B-aligned)
            uint2* adst = (uint2*)&Asm[A_m][A_kg * 8];
            adst[0] = make_uint2(s0.x, s0.y);
            adst[1] = make_uint2(s0.z, s0.w);
        }
        __syncthreads();
        f16x8 bfrag[2], afrag[4];
#pragma unroll
        for (int nt = 0; nt < 2; nt++)
            bfrag[nt] = ld8(&Bsm[w * 32 + nt * 16 + lr][lk * 8]);
#pragma unroll
        for (int m = 0; m < 4; m++)
            afrag[m] = ld8(&Asm[m * 16 + lr][lk * 8]);
#pragma unroll
        for (int m = 0; m < 4; m++)
#pragma unroll
            for (int nt = 0; nt < 2; nt++)
                acc[m][nt] = __builtin_amdgcn_mfma_f32_16x16x32_f16(
                    afrag[m], bfrag[nt], acc[m][nt], 0, 0, 0);
    }
    // park accumulators in LDS for the row-wise LN
#pragma unroll
    for (int m = 0; m < 4; m++)
#pragma unroll
        for (int nt = 0; nt < 2; nt++)
#pragma unroll
            for (int r = 0; r < 4; r++)
                Csm[m * 16 + lk * 4 + r][w * 32 + nt * 16 + lr] = acc[m][nt][r];
    __syncthreads();
    // LN: quad (4 lanes) per node row
    const int nn = t >> 2, q = t & 3;
    const int n = n0 + nn;
    if (n < NN) {
        const float dvinv = 1.0f / fmaxf((float)nc[n], DEG_EPS);
        float y[32];
        float sm = 0.0f, ss = 0.0f;
#pragma unroll
        for (int j = 0; j < 8; j++) {
            const float4 c = *(const float4*)&Csm[nn][q * 32 + j * 4];
            const float4 xr = *(const float4*)(x0 + (size_t)n * DD + q * 32 + j * 4);
            float v0 = c.x * dvinv + xr.x, v1 = c.y * dvinv + xr.y;
            float v2 = c.z * dvinv + xr.z, v3 = c.w * dvinv + xr.w;
            y[j * 4 + 0] = v0; y[j * 4 + 1] = v1; y[j * 4 + 2] = v2; y[j * 4 + 3] = v3;
            sm += v0 + v1 + v2 + v3;
            ss += v0 * v0 + v1 * v1 + v2 * v2 + v3 * v3;
        }
        sm += __shfl_xor(sm, 1); sm += __shfl_xor(sm, 2);
        ss += __shfl_xor(ss, 1); ss += __shfl_xor(ss, 2);
        const float mu = sm * (1.0f / 128.0f);
        float var = ss * (1.0f / 128.0f) - mu * mu;
        var = fmaxf(var, 0.0f);
        const float rstd = 1.0f / sqrtf(var + LN_EPS);
        uint_t ou[16];
#pragma unroll
        for (int j = 0; j < 8; j++) {
            const float4 g = *(const float4*)(gamma + q * 32 + j * 4);
            const float4 bb = *(const float4*)(beta + q * 32 + j * 4);
            const float o0 = (y[j * 4 + 0] - mu) * rstd * g.x + bb.x;
            const float o1 = (y[j * 4 + 1] - mu) * rstd * g.y + bb.y;
            const float o2 = (y[j * 4 + 2] - mu) * rstd * g.z + bb.z;
            const float o3 = (y[j * 4 + 3] - mu) * rstd * g.w + bb.w;
            ou[j * 2 + 0] = pack2h(o0, o1);
            ou[j * 2 + 1] = pack2h(o2, o3);
        }
        uint4* dst = (uint4*)(xh + (size_t)n * DD + q * 32);
#pragma unroll
        for (int j = 0; j < 4; j++)
            dst[j] = make_uint4(ou[j * 4], ou[j * 4 + 1], ou[j * 4 + 2], ou[j * 4 + 3]);
    }
}

// ---------------------------------------------------------------------------
// Attention logits from eout rows (R15-proven).
// ---------------------------------------------------------------------------
__global__ __launch_bounds__(64) void logits(
    const float* __restrict__ eout, const float* __restrict__ W,
    const float* __restrict__ bb, const float* __restrict__ qv,
    float* __restrict__ t) {
    __shared__ float rowbuf[DD];
    const int e = blockIdx.x;
    const int tid = threadIdx.x;
    const float2 v = reinterpret_cast<const float2*>(eout + (size_t)e * DD)[tid];
    rowbuf[tid * 2] = v.x;
    rowbuf[tid * 2 + 1] = v.y;
    __syncthreads();
    float r = 0.0f;
    if (tid < ATT) {
        float acc = 0.0f;
#pragma unroll 4
        for (int d = 0; d < DD; d++) acc += rowbuf[d] * W[d * ATT + tid];
        r = tanhf(acc + bb[tid]) * qv[tid];
    }
    for (int off = 16; off > 0; off >>= 1) r += __shfl_down(r, off);
    if (tid == 0) t[e] = r;
}

__global__ __launch_bounds__(1024) void softmax_stats(
    const float* __restrict__ t, float* __restrict__ MS) {
    __shared__ float red[16];
    __shared__ float smax;
    const int tid = threadIdx.x;
    const int wid = tid >> 6;
    float m = -1e30f;
    for (int i = tid; i < EE; i += 1024) m = fmaxf(m, t[i]);
    for (int off = 32; off > 0; off >>= 1) m = fmaxf(m, __shfl_down(m, off));
    if ((tid & 63) == 0) red[wid] = m;
    __syncthreads();
    if (tid < 64) {
        float v = (tid < 16) ? red[tid] : -1e30f;
        for (int off = 8; off > 0; off >>= 1) v = fmaxf(v, __shfl_down(v, off));
        if (tid == 0) smax = v;
    }
    __syncthreads();
    const float M = smax;
    float sum = 0.0f;
    for (int i = tid; i < EE; i += 1024) sum += expf(t[i] - M);
    for (int off = 32; off > 0; off >>= 1) sum += __shfl_down(sum, off);
    if ((tid & 63) == 0) red[wid] = sum;
    __syncthreads();
    if (tid < 64) {
        float v = (tid < 16) ? red[tid] : 0.0f;
        for (int off = 8; off > 0; off >>= 1) v += __shfl_down(v, off);
        if (tid == 0) { MS[0] = M; MS[1] = v; }
    }
}

__global__ __launch_bounds__(128) void weighted_sum(
    const float* __restrict__ eout, const float* __restrict__ t,
    const float* __restrict__ MS, float* __restrict__ out) {
    const int d = threadIdx.x;
    const float M = MS[0];
    const float invS = 1.0f / MS[1];
    float acc = 0.0f;
    for (int e = blockIdx.x; e < EE; e += gridDim.x) {
        const float w = expf(t[e] - M);
        acc += w * eout[e * DD + d];
    }
    atomicAdd(&out[d], acc * invS);
}

// ===========================================================================
// FALLBACK: R14 gather path (740us proven), used if ws_size < GEMM need.
// ===========================================================================
__global__ __launch_bounds__(256) void build_adj(
    const float* __restrict__ H, int* __restrict__ cur, int* __restrict__ nc,
    int* __restrict__ el, int* __restrict__ nl,
    const float* __restrict__ x0, __half* __restrict__ xh0) {
    const int n = blockIdx.x;
    const int tid = threadIdx.x;
    __shared__ int lcnt;
    __shared__ int lbuf[NCAP];
    if (tid == 0) lcnt = 0;
    __syncthreads();
    const vfloat4* row = reinterpret_cast<const vfloat4*>(H + (size_t)n * EE);
    for (int i = tid; i < EE / 4; i += 256) {
        const vfloat4 h = __builtin_nontemporal_load(row + i);
        float v[4] = {h.x, h.y, h.z, h.w};
        const int ebase = i * 4;
#pragma unroll
        for (int k = 0; k < 4; k++) {
            if (v[k] != 0.0f) {
                int s = atomicAdd(&lcnt, 1);
                if (s < NCAP) lbuf[s] = ebase + k;
            }
        }
    }
    __syncthreads();
    const int c = min(lcnt, NCAP);
    for (int k = tid; k < c; k += 256) {
        const int e = lbuf[k];
        nl[(size_t)n * NCAP + k] = e;
        const int slot = atomicAdd(&cur[e << 5], 1);
        if (slot < ECAP) el[(size_t)e * ECAP + slot] = n;
    }
    if (tid < 64) {
        const float2 v = reinterpret_cast<const float2*>(x0 + (size_t)n * DD)[tid];
        reinterpret_cast<unsigned*>(xh0 + (size_t)n * DD)[tid] = pack2h(v.x, v.y);
    }
    if (tid == 0) nc[n] = lcnt;
}

template <bool FINAL>
__global__ __launch_bounds__(256) void edge_gather16(
    const __half* __restrict__ xh, const int* __restrict__ cur,
    const int* __restrict__ el, __half* __restrict__ outh,
    float* __restrict__ eout, const float* __restrict__ W,
    const float* __restrict__ bb, const float* __restrict__ qv,
    float* __restrict__ t) {
    __shared__ int ilst[ECAP];
    __shared__ float part[4][16][8];
    __shared__ float rowbuf[DD];
    const int e = blockIdx.x;
    const int tid = threadIdx.x;
    const int* lst = el + (size_t)e * ECAP;
    ilst[tid] = lst[tid];
    if (tid < ECAP - 256) ilst[256 + tid] = lst[256 + tid];
    const int cnt = cur[e << 5];
    const int c = min(cnt, ECAP);
    __syncthreads();
    const int lane16 = tid & 15;
    const int s = tid >> 4;
    const int wave = tid >> 6;
    float a[8] = {0, 0, 0, 0, 0, 0, 0, 0};
    float b[8] = {0, 0, 0, 0, 0, 0, 0, 0};
    int i = s;
    for (; i + 48 < c; i += 64) {
        const int n0 = ilst[i];
        const int n1 = ilst[i + 16];
        const int n2 = ilst[i + 32];
        const int n3 = ilst[i + 48];
        const uint4 u0 = *reinterpret_cast<const uint4*>(xh + n0 * DD + lane16 * 8);
        const uint4 u1 = *reinterpret_cast<const uint4*>(xh + n1 * DD + lane16 * 8);
        const uint4 u2 = *reinterpret_cast<const uint4*>(xh + n2 * DD + lane16 * 8);
        const uint4 u3 = *reinterpret_cast<const uint4*>(xh + n3 * DD + lane16 * 8);
        acc8(a, u0); acc8(b, u1); acc8(a, u2); acc8(b, u3);
    }
    for (; i + 16 < c; i += 32) {
        const int n0 = ilst[i];
        const int n1 = ilst[i + 16];
        const uint4 u0 = *reinterpret_cast<const uint4*>(xh + n0 * DD + lane16 * 8);
        const uint4 u1 = *reinterpret_cast<const uint4*>(xh + n1 * DD + lane16 * 8);
        acc8(a, u0); acc8(b, u1);
    }
    if (i < c) {
        acc8(a, *reinterpret_cast<const uint4*>(xh + ilst[i] * DD + lane16 * 8));
    }
#pragma unroll
    for (int k = 0; k < 8; k++) {
        float v = a[k] + b[k];
        v += __shfl_down(v, 16);
        v += __shfl_down(v, 32);
        a[k] = v;
    }
    if ((tid & 63) < 16) {
#pragma unroll
        for (int k = 0; k < 8; k++) part[wave][lane16][k] = a[k];
    }
    __syncthreads();
    if (tid < 16) {
        const float inv = 1.0f / fmaxf((float)cnt, DEG_EPS);
        float o[8];
#pragma unroll
        for (int k = 0; k < 8; k++)
            o[k] = (part[0][tid][k] + part[1][tid][k] + part[2][tid][k] + part[3][tid][k]) * inv;
        if (!FINAL) {
            uint4 u;
            u.x = pack2h(o[0], o[1]); u.y = pack2h(o[2], o[3]);
            u.z = pack2h(o[4], o[5]); u.w = pack2h(o[6], o[7]);
            *reinterpret_cast<uint4*>(outh + e * DD + tid * 8) = u;
        } else {
#pragma unroll
            for (int k = 0; k < 8; k++) rowbuf[tid * 8 + k] = o[k];
            *reinterpret_cast<float4*>(eout + e * DD + tid * 8) =
                make_float4(o[0], o[1], o[2], o[3]);
            *reinterpret_cast<float4*>(eout + e * DD + tid * 8 + 4) =
                make_float4(o[4], o[5], o[6], o[7]);
        }
    }
    if (FINAL) {
        __syncthreads();
        float r = 0.0f;
        if (tid < ATT) {
            float acc = 0.0f;
#pragma unroll 4
            for (int d = 0; d < DD; d++) acc += rowbuf[d] * W[d * ATT + tid];
            r = tanhf(acc + bb[tid]) * qv[tid];
        }
        for (int off = 16; off > 0; off >>= 1) r += __shfl_down(r, off);
        if (tid == 0) t[e] = r;
    }
}

__global__ __launch_bounds__(128) void node_gather_ln16(
    const __half* __restrict__ emean, const int* __restrict__ nc,
    const int* __restrict__ nl, const float* __restrict__ x0,
    const float* __restrict__ gamma, const float* __restrict__ beta,
    __half* __restrict__ xout) {
    __shared__ int ilst[NCAP];
    __shared__ float part[2][16][8];
    const int n = blockIdx.x;
    const int tid = threadIdx.x;
    const int* lst = nl + (size_t)n * NCAP;
    ilst[tid] = lst[tid];
    const int cnt = nc[n];
    const int c = min(cnt, NCAP);
    __syncthreads();
    const int lane16 = tid & 15;
    const int s = tid >> 4;
    const int wave = tid >> 6;
    float a[8] = {0, 0, 0, 0, 0, 0, 0, 0};
    float b[8] = {0, 0, 0, 0, 0, 0, 0, 0};
    int i = s;
    for (; i + 24 < c; i += 32) {
        const int e0 = ilst[i];
        const int e1 = ilst[i + 8];
        const int e2 = ilst[i + 16];
        const int e3 = ilst[i + 24];
        const uint4 u0 = *reinterpret_cast<const uint4*>(emean + e0 * DD + lane16 * 8);
        const uint4 u1 = *reinterpret_cast<const uint4*>(emean + e1 * DD + lane16 * 8);
        const uint4 u2 = *reinterpret_cast<const uint4*>(emean + e2 * DD + lane16 * 8);
        const uint4 u3 = *reinterpret_cast<const uint4*>(emean + e3 * DD + lane16 * 8);
        acc8(a, u0); acc8(b, u1); acc8(a, u2); acc8(b, u3);
    }
    for (; i + 8 < c; i += 16) {
        const int e0 = ilst[i];
        const int e1 = ilst[i + 8];
        const uint4 u0 = *reinterpret_cast<const uint4*>(emean + e0 * DD + lane16 * 8);
        const uint4 u1 = *reinterpret_cast<const uint4*>(emean + e1 * DD + lane16 * 8);
        acc8(a, u0); acc8(b, u1);
    }
    if (i < c) {
        acc8(a, *reinterpret_cast<const uint4*>(emean + ilst[i] * DD + lane16 * 8));
    }
#pragma unroll
    for (int k = 0; k < 8; k++) {
        float v = a[k] + b[k];
        v += __shfl_down(v, 16);
        v += __shfl_down(v, 32);
        a[k] = v;
    }
    if ((tid & 63) < 16) {
#pragma unroll
        for (int k = 0; k < 8; k++) part[wave][lane16][k] = a[k];
    }
    __syncthreads();
    if (tid < 16) {
        const float inv = 1.0f / fmaxf((float)cnt, DEG_EPS);
        const float4 x0a = *reinterpret_cast<const float4*>(x0 + n * DD + tid * 8);
        const float4 x0b = *reinterpret_cast<const float4*>(x0 + n * DD + tid * 8 + 4);
        float y[8];
        y[0] = (part[0][tid][0] + part[1][tid][0]) * inv + x0a.x;
        y[1] = (part[0][tid][1] + part[1][tid][1]) * inv + x0a.y;
        y[2] = (part[0][tid][2] + part[1][tid][2]) * inv + x0a.z;
        y[3] = (part[0][tid][3] + part[1][tid][3]) * inv + x0a.w;
        y[4] = (part[0][tid][4] + part[1][tid][4]) * inv + x0b.x;
        y[5] = (part[0][tid][5] + part[1][tid][5]) * inv + x0b.y;
        y[6] = (part[0][tid][6] + part[1][tid][6]) * inv + x0b.z;
        y[7] = (part[0][tid][7] + part[1][tid][7]) * inv + x0b.w;
        float sm = 0.0f, ss = 0.0f;
#pragma unroll
        for (int k = 0; k < 8; k++) { sm += y[k]; ss += y[k] * y[k]; }
        for (int off = 8; off > 0; off >>= 1) {
            sm += __shfl_down(sm, off);
            ss += __shfl_down(ss, off);
        }
        sm = __shfl(sm, 0);
        ss = __shfl(ss, 0);
        const float mu = sm * (1.0f / 128.0f);
        float var = ss * (1.0f / 128.0f) - mu * mu;
        var = fmaxf(var, 0.0f);
        const float rstd = 1.0f / sqrtf(var + LN_EPS);
        const float4 g0 = *reinterpret_cast<const float4*>(gamma + tid * 8);
        const float4 g1 = *reinterpret_cast<const float4*>(gamma + tid * 8 + 4);
        const float4 b0 = *reinterpret_cast<const float4*>(beta + tid * 8);
        const float4 b1 = *reinterpret_cast<const float4*>(beta + tid * 8 + 4);
        float gg[8] = {g0.x, g0.y, g0.z, g0.w, g1.x, g1.y, g1.z, g1.w};
        float bb[8] = {b0.x, b0.y, b0.z, b0.w, b1.x, b1.y, b1.z, b1.w};
        float o[8];
#pragma unroll
        for (int k = 0; k < 8; k++) o[k] = (y[k] - mu) * rstd * gg[k] + bb[k];
        uint4 u;
        u.x = pack2h(o[0], o[1]); u.y = pack2h(o[2], o[3]);
        u.z = pack2h(o[4], o[5]); u.w = pack2h(o[6], o[7]);
        *reinterpret_cast<uint4*>(xout + n * DD + tid * 8) = u;
    }
}

extern "C" void kernel_launch(void* const* d_in, const int* in_sizes, int n_in,
                              void* d_out, int out_size, void* d_ws, size_t ws_size,
                              hipStream_t stream) {
    const float* x0 = (const float*)d_in[0];     // [N, D]
    const float* H = (const float*)d_in[1];      // [N, E]
    const float* gamma = (const float*)d_in[2];  // [D]
    const float* beta = (const float*)d_in[3];   // [D]
    const float* W = (const float*)d_in[4];      // [D, ATT]
    const float* b = (const float*)d_in[5];      // [ATT]
    const float* qv = (const float*)d_in[6];     // [ATT]
    float* out = (float*)d_out;                  // [D]

    // Workspace layout (256B-aligned). H16 last so the fallback never needs it.
    size_t off = 0;
    auto alloc = [&](size_t bytes) -> char* {
        char* p = (char*)d_ws + off;
        off += (bytes + 255) & ~(size_t)255;
        return p;
    };
    int* cur = (int*)alloc((size_t)EE * CSTRIDE * 4);
    int* nc = (int*)alloc((size_t)NN * 4);
    int* el = (int*)alloc((size_t)EE * ECAP * 4);
    int* nl = (int*)alloc((size_t)NN * NCAP * 4);
    __half* xh = (__half*)alloc((size_t)NN * DD * 2);
    __half* emean = (__half*)alloc((size_t)EE * DD * 2);
    float* eout = (float*)alloc((size_t)EE * DD * 4);
    float* t = (float*)alloc((size_t)EE * 4);
    float* MS = (float*)alloc(64);
    float* Cacc = (float*)alloc((size_t)5056 * DD * 4);   // padded e rows
    const size_t h16_bytes = (size_t)NN * EE * 2;
    __half* H16 = (__half*)alloc(h16_bytes);
    const bool use_gemm = (off <= ws_size);

    hipMemsetAsync(cur, 0, (size_t)EE * CSTRIDE * 4, stream);
    hipMemsetAsync(d_out, 0, (size_t)DD * sizeof(float), stream);

    if (use_gemm) {
        hipMemsetAsync(Cacc, 0, (size_t)5056 * DD * 4, stream);
        convert_h<<<NN, 256, 0, stream>>>(H, H16, cur, nc, x0, xh);
        for (int l = 0; l < NUM_LAYERS; l++) {
            gemm_e<<<79 * 4, 256, 0, stream>>>(H16, xh, Cacc);
            ep_edge<<<2528, 256, 0, stream>>>(Cacc, cur, emean, nullptr, 0);
            gemm_n<<<313, 256, 0, stream>>>(H16, emean, nc, x0, gamma, beta, xh);
        }
        gemm_e<<<79 * 4, 256, 0, stream>>>(H16, xh, Cacc);
        ep_edge<<<2528, 256, 0, stream>>>(Cacc, cur, nullptr, eout, 1);
        logits<<<EE, 64, 0, stream>>>(eout, W, b, qv, t);
        softmax_stats<<<1, 1024, 0, stream>>>(t, MS);
        weighted_sum<<<256, 128, 0, stream>>>(eout, t, MS, out);
    } else {
        // R14 fallback (740us proven)
        build_adj<<<NN, 256, 0, stream>>>(H, cur, nc, el, nl, x0, xh);
        for (int l = 0; l < NUM_LAYERS; l++) {
            edge_gather16<false><<<EE, 256, 0, stream>>>(
                xh, cur, el, emean, nullptr, nullptr, nullptr, nullptr, nullptr);
            node_gather_ln16<<<NN, 128, 0, stream>>>(
                emean, nc, nl, x0, gamma, beta, xh);
        }
        edge_gather16<true><<<EE, 256, 0, stream>>>(
            xh, cur, el, nullptr, eout, W, b, qv, t);
        softmax_stats<<<1, 1024, 0, stream>>>(t, MS);
        weighted_sum<<<256, 128, 0, stream>>>(eout, t, MS, out);
    }
}

// Round 10
// 1780.197 us; speedup vs baseline: 1.5002x; 1.5002x over previous
//
#include <hip/hip_runtime.h>
#include <hip/hip_fp16.h>
#include <math.h>

// Problem constants (fixed by the reference)
#define NN 20000
#define EE 5000
#define DD 128
#define ATT 32
#define NUM_LAYERS 4
#define LN_EPS 1e-5f
#define DEG_EPS 1e-12f
#define CSTRIDE 32

// R17 bit-packed GEMM geometry
#define EPAD 5024      // gemm_e m coverage (157 tiles x 32)
#define CPAD 5056      // Cacc rows (79 x 64 for ep_edge)
#define KE   20480     // padded K (n-dim) for gemm_e; xT row = KE fp16
#define KN   5120      // padded K (e-dim) for gemm_n; emT row = KN fp16
#define HnROW 640      // bytes per Hn row (5120 bits)
#define HeROW 2560     // bytes per He row (20480 bits)

typedef _Float16 f16;
typedef f16 f16x8 __attribute__((ext_vector_type(8)));
typedef float f32x4 __attribute__((ext_vector_type(4)));

__device__ inline f16x8 asf16x8(uint4 u) {
    union { uint4 u; f16x8 h; } c; c.u = u; return c.h;
}
__device__ inline unsigned short h16(float v) {
    return __half_as_ushort(__float2half_rn(v));
}

// ===========================================================================
// R17: H is BINARY -> pack to bits (Hn 12.8MB row-major, He 12.9MB col-major;
// both L2/LLC-resident) and keep x/em TRANSPOSED ([D][N] / [D][E]) so mfma
// B-fragments are direct 16B global loads from L2-resident tables. A-frags
// expand from bit-bytes via a 256-entry LDS LUT. No LDS staging, no barriers
// in the GEMM main loops. Per-pass HBM traffic: 205 MB (R16) -> ~20 MB.
// Fragment<->memory mapping reused unchanged from R16 (hardware-validated).
// ===========================================================================

// ---- pack: one nontemporal pass over H -> Hn bits, He bits, degrees -------
__global__ __launch_bounds__(256) void pack_h(
    const float* __restrict__ H, unsigned* __restrict__ Hn,
    unsigned* __restrict__ He, int* __restrict__ cur, int* __restrict__ nc) {
    const int n = blockIdx.x;
    const int t = threadIdx.x;
    const int w = t >> 6, l = t & 63;
    __shared__ int red[4];
    int cnt = 0;
    unsigned long long* hnrow =
        (unsigned long long*)((char*)Hn + (size_t)n * HnROW);
    const float* hrow = H + (size_t)n * EE;
    for (int g = w; g < 80; g += 4) {           // 80 groups of 64 e = 5120 bits
        const int e = g * 64 + l;
        float v = 0.0f;
        if (e < EE) v = __builtin_nontemporal_load(hrow + e);
        const bool p = (v != 0.0f);
        const unsigned long long m = __ballot(p);
        if (l == 0) { hnrow[g] = m; cnt += (int)__popcll(m); }
        if (p) {
            atomicAdd(&cur[e << 5], 1);
            atomicOr(&He[(size_t)e * (HeROW / 4) + (n >> 5)], 1u << (n & 31));
        }
    }
    if (l == 0) red[w] = cnt;
    __syncthreads();
    if (t == 0) nc[n] = red[0] + red[1] + red[2] + red[3];
}

// ---- xT init: x0 fp32 [N][D] -> fp16 xT [D][KE] (transposed, pad zero) ----
__global__ __launch_bounds__(256) void xt_build(
    const float* __restrict__ x0, unsigned char* __restrict__ xTb) {
    __shared__ unsigned short Lt[64][136];
    const int n0 = blockIdx.x * 64;
    const int t = threadIdx.x;
    const int rr = t >> 2, q = t & 3;
    const int n = n0 + rr;
#pragma unroll
    for (int j = 0; j < 8; j++) {
        float4 v = make_float4(0.f, 0.f, 0.f, 0.f);
        if (n < NN) v = *(const float4*)(x0 + (size_t)n * DD + q * 32 + j * 4);
        Lt[rr][q * 32 + j * 4 + 0] = h16(v.x);
        Lt[rr][q * 32 + j * 4 + 1] = h16(v.y);
        Lt[rr][q * 32 + j * 4 + 2] = h16(v.z);
        Lt[rr][q * 32 + j * 4 + 3] = h16(v.w);
    }
    __syncthreads();
    const int d = t >> 1, half = t & 1;
    union { unsigned short s[32]; uint4 q4[4]; } u;
#pragma unroll
    for (int i = 0; i < 32; i++) u.s[i] = Lt[half * 32 + i][d];
    uint4* dst = (uint4*)(xTb + (size_t)d * (KE * 2) +
                          (size_t)(n0 + half * 32) * 2);
#pragma unroll
    for (int i = 0; i < 4; i++) dst[i] = u.q4[i];
}

// ---- GEMM-E: Cacc[e][d] += sum_n He_bit(e,n) * xT[d][n] ------------------
// grid 157 m-tiles x 8 k-chunks = 1256. BM=32, BN=128, no LDS staging.
__global__ __launch_bounds__(256) void gemm_e(
    const unsigned char* __restrict__ Heb, const unsigned char* __restrict__ xTb,
    float* __restrict__ Cacc) {
    __shared__ uint4 lut[256];
    {
        const int t = threadIdx.x;
        unsigned w0 = ((t & 1) ? 0x3C00u : 0u) | ((t & 2) ? 0x3C000000u : 0u);
        unsigned w1 = ((t & 4) ? 0x3C00u : 0u) | ((t & 8) ? 0x3C000000u : 0u);
        unsigned w2 = ((t & 16) ? 0x3C00u : 0u) | ((t & 32) ? 0x3C000000u : 0u);
        unsigned w3 = ((t & 64) ? 0x3C00u : 0u) | ((t & 128) ? 0x3C000000u : 0u);
        lut[t] = make_uint4(w0, w1, w2, w3);
    }
    __syncthreads();
    const int bid = blockIdx.x;
    const int mt = bid % 157, kc = bid / 157;
    const int e0 = mt * 32;
    const int kbeg = kc * (KE / 8), kend = kbeg + (KE / 8);
    const int t = threadIdx.x;
    const int w = t >> 6, l = t & 63;
    const int lr = l & 15, lk = l >> 4;
    const int sh = lk * 8;
    f32x4 a00 = {0,0,0,0}, a01 = {0,0,0,0}, a10 = {0,0,0,0}, a11 = {0,0,0,0};
    const unsigned char* ar0 = Heb + (size_t)(e0 + lr) * HeROW;
    const unsigned char* ar1 = Heb + (size_t)(e0 + 16 + lr) * HeROW;
    const unsigned char* br0 = xTb + (size_t)(w * 32 + lr) * (KE * 2) + lk * 16;
    const unsigned char* br1 = xTb + (size_t)(w * 32 + 16 + lr) * (KE * 2) + lk * 16;
    for (int k0 = kbeg; k0 < kend; k0 += 128) {
        const uint4 bw0 = *(const uint4*)(ar0 + (k0 >> 3));
        const uint4 bw1 = *(const uint4*)(ar1 + (k0 >> 3));
        uint4 b0[4], b1[4];
#pragma unroll
        for (int t4 = 0; t4 < 4; t4++) {
            b0[t4] = *(const uint4*)(br0 + (size_t)(k0 + t4 * 32) * 2);
            b1[t4] = *(const uint4*)(br1 + (size_t)(k0 + t4 * 32) * 2);
        }
        const unsigned wa0[4] = {bw0.x, bw0.y, bw0.z, bw0.w};
        const unsigned wa1[4] = {bw1.x, bw1.y, bw1.z, bw1.w};
#pragma unroll
        for (int t4 = 0; t4 < 4; t4++) {
            const f16x8 fa0 = asf16x8(lut[(wa0[t4] >> sh) & 0xFF]);
            const f16x8 fa1 = asf16x8(lut[(wa1[t4] >> sh) & 0xFF]);
            const f16x8 fb0 = asf16x8(b0[t4]);
            const f16x8 fb1 = asf16x8(b1[t4]);
            a00 = __builtin_amdgcn_mfma_f32_16x16x32_f16(fa0, fb0, a00, 0, 0, 0);
            a01 = __builtin_amdgcn_mfma_f32_16x16x32_f16(fa0, fb1, a01, 0, 0, 0);
            a10 = __builtin_amdgcn_mfma_f32_16x16x32_f16(fa1, fb0, a10, 0, 0, 0);
            a11 = __builtin_amdgcn_mfma_f32_16x16x32_f16(fa1, fb1, a11, 0, 0, 0);
        }
    }
    // C layout (R16-verified): col = l&15, row = (l>>4)*4 + r
#pragma unroll
    for (int r = 0; r < 4; r++) {
        atomicAdd(&Cacc[(size_t)(e0 + lk * 4 + r) * DD + w * 32 + lr], a00[r]);
        atomicAdd(&Cacc[(size_t)(e0 + lk * 4 + r) * DD + w * 32 + 16 + lr], a01[r]);
        atomicAdd(&Cacc[(size_t)(e0 + 16 + lk * 4 + r) * DD + w * 32 + lr], a10[r]);
        atomicAdd(&Cacc[(size_t)(e0 + 16 + lk * 4 + r) * DD + w * 32 + 16 + lr], a11[r]);
    }
}

// ---- edge epilogue: scale + (emT fp16 transposed | eout fp32); rezero Cacc
__global__ __launch_bounds__(256) void ep_edge(
    float* __restrict__ Cacc, const int* __restrict__ cur,
    unsigned char* __restrict__ emTb, float* __restrict__ eout,
    const int isFinal) {
    __shared__ unsigned short Lt[64][136];
    const int e0 = blockIdx.x * 64;
    const int t = threadIdx.x;
    const int rr = t >> 2, q = t & 3;
    const int e = e0 + rr;
    float de = 0.0f;
    if (e < EE) de = (float)cur[e << 5];
    const float s = isFinal ? (1.0f / fmaxf(de, 1.0f))
                            : (1.0f / fmaxf(de, DEG_EPS));
    float* crow = Cacc + (size_t)e * DD + q * 32;
#pragma unroll
    for (int j = 0; j < 8; j++) {
        float4 v = *(float4*)(crow + j * 4);
        *(float4*)(crow + j * 4) = make_float4(0.f, 0.f, 0.f, 0.f);
        v.x *= s; v.y *= s; v.z *= s; v.w *= s;
        if (isFinal) {
            if (e < EE)
                *(float4*)(eout + (size_t)e * DD + q * 32 + j * 4) = v;
        } else {
            Lt[rr][q * 32 + j * 4 + 0] = h16(v.x);
            Lt[rr][q * 32 + j * 4 + 1] = h16(v.y);
            Lt[rr][q * 32 + j * 4 + 2] = h16(v.z);
            Lt[rr][q * 32 + j * 4 + 3] = h16(v.w);
        }
    }
    if (!isFinal) {
        __syncthreads();
        const int d = t >> 1, half = t & 1;
        union { unsigned short s[32]; uint4 q4[4]; } u;
#pragma unroll
        for (int i = 0; i < 32; i++) u.s[i] = Lt[half * 32 + i][d];
        uint4* dst = (uint4*)(emTb + (size_t)d * (KN * 2) +
                              (size_t)(e0 + half * 32) * 2);
#pragma unroll
        for (int i = 0; i < 4; i++) dst[i] = u.q4[i];
    }
}

// ---- GEMM-N + fused LN: xT' = LN(dv_inv*(Hn bits . emT) + x0) ------------
// grid 625 (BM=32 n-rows), K=5120 full (no split-K -> LN fusable).
__global__ __launch_bounds__(256) void gemm_n(
    const unsigned char* __restrict__ Hnb, const unsigned char* __restrict__ emTb,
    const int* __restrict__ nc, const float* __restrict__ x0,
    const float* __restrict__ gamma, const float* __restrict__ beta,
    unsigned char* __restrict__ xTb) {
    __shared__ uint4 lut[256];
    __shared__ float Csm[32][132];
    __shared__ unsigned short Lt[32][136];
    {
        const int t = threadIdx.x;
        unsigned w0 = ((t & 1) ? 0x3C00u : 0u) | ((t & 2) ? 0x3C000000u : 0u);
        unsigned w1 = ((t & 4) ? 0x3C00u : 0u) | ((t & 8) ? 0x3C000000u : 0u);
        unsigned w2 = ((t & 16) ? 0x3C00u : 0u) | ((t & 32) ? 0x3C000000u : 0u);
        unsigned w3 = ((t & 64) ? 0x3C00u : 0u) | ((t & 128) ? 0x3C000000u : 0u);
        lut[t] = make_uint4(w0, w1, w2, w3);
    }
    __syncthreads();
    const int n0 = blockIdx.x * 32;        // 625*32 = 20000 exact
    const int t = threadIdx.x;
    const int w = t >> 6, l = t & 63;
    const int lr = l & 15, lk = l >> 4;
    const int sh = lk * 8;
    f32x4 a00 = {0,0,0,0}, a01 = {0,0,0,0}, a10 = {0,0,0,0}, a11 = {0,0,0,0};
    const unsigned char* ar0 = Hnb + (size_t)(n0 + lr) * HnROW;
    const unsigned char* ar1 = Hnb + (size_t)(n0 + 16 + lr) * HnROW;
    const unsigned char* br0 = emTb + (size_t)(w * 32 + lr) * (KN * 2) + lk * 16;
    const unsigned char* br1 = emTb + (size_t)(w * 32 + 16 + lr) * (KN * 2) + lk * 16;
    for (int k0 = 0; k0 < KN; k0 += 128) {
        const uint4 bw0 = *(const uint4*)(ar0 + (k0 >> 3));
        const uint4 bw1 = *(const uint4*)(ar1 + (k0 >> 3));
        uint4 b0[4], b1[4];
#pragma unroll
        for (int t4 = 0; t4 < 4; t4++) {
            b0[t4] = *(const uint4*)(br0 + (size_t)(k0 + t4 * 32) * 2);
            b1[t4] = *(const uint4*)(br1 + (size_t)(k0 + t4 * 32) * 2);
        }
        const unsigned wa0[4] = {bw0.x, bw0.y, bw0.z, bw0.w};
        const unsigned wa1[4] = {bw1.x, bw1.y, bw1.z, bw1.w};
#pragma unroll
        for (int t4 = 0; t4 < 4; t4++) {
            const f16x8 fa0 = asf16x8(lut[(wa0[t4] >> sh) & 0xFF]);
            const f16x8 fa1 = asf16x8(lut[(wa1[t4] >> sh) & 0xFF]);
            const f16x8 fb0 = asf16x8(b0[t4]);
            const f16x8 fb1 = asf16x8(b1[t4]);
            a00 = __builtin_amdgcn_mfma_f32_16x16x32_f16(fa0, fb0, a00, 0, 0, 0);
            a01 = __builtin_amdgcn_mfma_f32_16x16x32_f16(fa0, fb1, a01, 0, 0, 0);
            a10 = __builtin_amdgcn_mfma_f32_16x16x32_f16(fa1, fb0, a10, 0, 0, 0);
            a11 = __builtin_amdgcn_mfma_f32_16x16x32_f16(fa1, fb1, a11, 0, 0, 0);
        }
    }
#pragma unroll
    for (int r = 0; r < 4; r++) {
        Csm[lk * 4 + r][w * 32 + lr] = a00[r];
        Csm[lk * 4 + r][w * 32 + 16 + lr] = a01[r];
        Csm[16 + lk * 4 + r][w * 32 + lr] = a10[r];
        Csm[16 + lk * 4 + r][w * 32 + 16 + lr] = a11[r];
    }
    __syncthreads();
    // LN: 8 threads per node row (16 d each)
    const int rr = t >> 3, q = t & 7;
    const int n = n0 + rr;
    const float dvinv = 1.0f / fmaxf((float)nc[n], DEG_EPS);
    float y[16];
    float sm = 0.0f, ss = 0.0f;
#pragma unroll
    for (int j = 0; j < 4; j++) {
        const float4 xr = *(const float4*)(x0 + (size_t)n * DD + q * 16 + j * 4);
        float v0 = Csm[rr][q * 16 + j * 4 + 0] * dvinv + xr.x;
        float v1 = Csm[rr][q * 16 + j * 4 + 1] * dvinv + xr.y;
        float v2 = Csm[rr][q * 16 + j * 4 + 2] * dvinv + xr.z;
        float v3 = Csm[rr][q * 16 + j * 4 + 3] * dvinv + xr.w;
        y[j * 4 + 0] = v0; y[j * 4 + 1] = v1; y[j * 4 + 2] = v2; y[j * 4 + 3] = v3;
        sm += v0 + v1 + v2 + v3;
        ss += v0 * v0 + v1 * v1 + v2 * v2 + v3 * v3;
    }
    sm += __shfl_xor(sm, 1); sm += __shfl_xor(sm, 2); sm += __shfl_xor(sm, 4);
    ss += __shfl_xor(ss, 1); ss += __shfl_xor(ss, 2); ss += __shfl_xor(ss, 4);
    const float mu = sm * (1.0f / 128.0f);
    float var = ss * (1.0f / 128.0f) - mu * mu;
    var = fmaxf(var, 0.0f);
    const float rstd = 1.0f / sqrtf(var + LN_EPS);
#pragma unroll
    for (int j = 0; j < 4; j++) {
        const float4 g = *(const float4*)(gamma + q * 16 + j * 4);
        const float4 bb = *(const float4*)(beta + q * 16 + j * 4);
        Lt[rr][q * 16 + j * 4 + 0] = h16((y[j * 4 + 0] - mu) * rstd * g.x + bb.x);
        Lt[rr][q * 16 + j * 4 + 1] = h16((y[j * 4 + 1] - mu) * rstd * g.y + bb.y);
        Lt[rr][q * 16 + j * 4 + 2] = h16((y[j * 4 + 2] - mu) * rstd * g.z + bb.z);
        Lt[rr][q * 16 + j * 4 + 3] = h16((y[j * 4 + 3] - mu) * rstd * g.w + bb.w);
    }
    __syncthreads();
    const int d = t >> 1, half = t & 1;
    union { unsigned short s[16]; uint4 q4[2]; } u;
#pragma unroll
    for (int i = 0; i < 16; i++) u.s[i] = Lt[half * 16 + i][d];
    uint4* dst = (uint4*)(xTb + (size_t)d * (KE * 2) +
                          (size_t)(n0 + half * 16) * 2);
    dst[0] = u.q4[0];
    dst[1] = u.q4[1];
}

// ---- tail: logits, softmax, weighted sum (R16-verified) -------------------
__global__ __launch_bounds__(64) void logits(
    const float* __restrict__ eout, const float* __restrict__ W,
    const float* __restrict__ bb, const float* __restrict__ qv,
    float* __restrict__ t) {
    __shared__ float rowbuf[DD];
    const int e = blockIdx.x;
    const int tid = threadIdx.x;
    const float2 v = reinterpret_cast<const float2*>(eout + (size_t)e * DD)[tid];
    rowbuf[tid * 2] = v.x;
    rowbuf[tid * 2 + 1] = v.y;
    __syncthreads();
    float r = 0.0f;
    if (tid < ATT) {
        float acc = 0.0f;
#pragma unroll 4
        for (int d = 0; d < DD; d++) acc += rowbuf[d] * W[d * ATT + tid];
        r = tanhf(acc + bb[tid]) * qv[tid];
    }
    for (int off = 16; off > 0; off >>= 1) r += __shfl_down(r, off);
    if (tid == 0) t[e] = r;
}

__global__ __launch_bounds__(1024) void softmax_stats(
    const float* __restrict__ t, float* __restrict__ MS) {
    __shared__ float red[16];
    __shared__ float smax;
    const int tid = threadIdx.x;
    const int wid = tid >> 6;
    float m = -1e30f;
    for (int i = tid; i < EE; i += 1024) m = fmaxf(m, t[i]);
    for (int off = 32; off > 0; off >>= 1) m = fmaxf(m, __shfl_down(m, off));
    if ((tid & 63) == 0) red[wid] = m;
    __syncthreads();
    if (tid < 64) {
        float v = (tid < 16) ? red[tid] : -1e30f;
        for (int off = 8; off > 0; off >>= 1) v = fmaxf(v, __shfl_down(v, off));
        if (tid == 0) smax = v;
    }
    __syncthreads();
    const float M = smax;
    float sum = 0.0f;
    for (int i = tid; i < EE; i += 1024) sum += expf(t[i] - M);
    for (int off = 32; off > 0; off >>= 1) sum += __shfl_down(sum, off);
    if ((tid & 63) == 0) red[wid] = sum;
    __syncthreads();
    if (tid < 64) {
        float v = (tid < 16) ? red[tid] : 0.0f;
        for (int off = 8; off > 0; off >>= 1) v += __shfl_down(v, off);
        if (tid == 0) { MS[0] = M; MS[1] = v; }
    }
}

__global__ __launch_bounds__(128) void weighted_sum(
    const float* __restrict__ eout, const float* __restrict__ t,
    const float* __restrict__ MS, float* __restrict__ out) {
    const int d = threadIdx.x;
    const float M = MS[0];
    const float invS = 1.0f / MS[1];
    float acc = 0.0f;
    for (int e = blockIdx.x; e < EE; e += gridDim.x) {
        const float w = expf(t[e] - M);
        acc += w * eout[e * DD + d];
    }
    atomicAdd(&out[d], acc * invS);
}

extern "C" void kernel_launch(void* const* d_in, const int* in_sizes, int n_in,
                              void* d_out, int out_size, void* d_ws, size_t ws_size,
                              hipStream_t stream) {
    const float* x0 = (const float*)d_in[0];     // [N, D]
    const float* H = (const float*)d_in[1];      // [N, E]
    const float* gamma = (const float*)d_in[2];  // [D]
    const float* beta = (const float*)d_in[3];   // [D]
    const float* W = (const float*)d_in[4];      // [D, ATT]
    const float* b = (const float*)d_in[5];      // [ATT]
    const float* qv = (const float*)d_in[6];     // [ATT]
    float* out = (float*)d_out;                  // [D]

    // Workspace (~38 MB, 256B-aligned). First block [cur..emT] is zeroed by
    // ONE memset (cur: atomic counters; He: atomicOr target; Cacc: atomic
    // accumulator; xT/emT: zero pads that persist across layers).
    size_t off = 0;
    auto alloc = [&](size_t bytes) -> char* {
        char* p = (char*)d_ws + off;
        off += (bytes + 255) & ~(size_t)255;
        return p;
    };
    int* cur = (int*)alloc((size_t)EE * CSTRIDE * 4);
    unsigned char* Heb = (unsigned char*)alloc((size_t)EPAD * HeROW);
    float* Cacc = (float*)alloc((size_t)CPAD * DD * 4);
    unsigned char* xTb = (unsigned char*)alloc((size_t)DD * KE * 2);
    unsigned char* emTb = (unsigned char*)alloc((size_t)DD * KN * 2);
    const size_t zend = off;
    unsigned char* Hnb = (unsigned char*)alloc((size_t)NN * HnROW);
    int* nc = (int*)alloc((size_t)NN * 4);
    float* eout = (float*)alloc((size_t)EE * DD * 4);
    float* tt = (float*)alloc((size_t)EE * 4);
    float* MS = (float*)alloc(64);
    (void)ws_size;

    hipMemsetAsync(d_ws, 0, zend, stream);
    hipMemsetAsync(d_out, 0, (size_t)DD * sizeof(float), stream);

    pack_h<<<NN, 256, 0, stream>>>(H, (unsigned*)Hnb, (unsigned*)Heb, cur, nc);
    xt_build<<<313, 256, 0, stream>>>(x0, xTb);

    for (int l = 0; l < NUM_LAYERS; l++) {
        gemm_e<<<157 * 8, 256, 0, stream>>>(Heb, xTb, Cacc);
        ep_edge<<<79, 256, 0, stream>>>(Cacc, cur, emTb, nullptr, 0);
        gemm_n<<<625, 256, 0, stream>>>(Hnb, emTb, nc, x0, gamma, beta, xTb);
    }

    gemm_e<<<157 * 8, 256, 0, stream>>>(Heb, xTb, Cacc);
    ep_edge<<<79, 256, 0, stream>>>(Cacc, cur, nullptr, eout, 1);
    logits<<<EE, 64, 0, stream>>>(eout, W, b, qv, tt);
    softmax_stats<<<1, 1024, 0, stream>>>(tt, MS);
    weighted_sum<<<256, 128, 0, stream>>>(eout, tt, MS, out);
}